// Round 7
// baseline (105.711 us; speedup 1.0000x reference)
//
#include <hip/hip_runtime.h>

// ExemplarNoAttention: logits[b,c] = log( sum_{e: label[e]==c} exp(-beta*d2[b,e]) + eps )
// d2[b,e] = ||x_b||^2 + ||e_e||^2 - 2<x_b,e_e>, clamped >= 0; beta = softplus(beta_raw).
//
// Round 7 = R6 (winner: LDS double-buffered staging, 102.6 us total) +
//  (a) XCD shard: 104 chunks, XCD k (= blockIdx&7) owns chunks == k mod 8 ->
//      832 KB fp16 shard is per-XCD L2-resident (R4 proved FETCH 26.7->4.1 MB;
//      NO fences this time -- that was R4's separate regression).
//  (b) prefetch distance 2 (two register sets; stage st+2 issued at stage st,
//      ~700 cyc latency cover vs ~300 cyc compute per stage).
//  (c) 1 barrier/stage (pre-write barrier was redundant: the written buffer was
//      last read in stage st-1, already fenced by that stage's end barrier).
// Harness floor: ~60 us (268 MB d_ws 0xAA re-poison fill @43 us + restore/launch
// machinery) -- visible as __amd_rocclr_fillBufferAligned in the R6 profile.

#define NB      1024
#define NE      50000
#define NCHUNK  104
#define NE_PAD  (NCHUNK * 512)   // 53248
#define KD      64
#define NC      10
#define SROWS   64       // e-rows per stage
#define NSTAGE  8        // 512 / SROWS
#define LROW    72       // padded LDS row stride in halfs (144 B): 2-way banks (free)

using half8   = __attribute__((ext_vector_type(8))) _Float16;  // 16x16x32 A/B frag (4 VGPRs)
using half4v  = __attribute__((ext_vector_type(4))) _Float16;  // 16x16x16 A/B frag (2 VGPRs)
using floatx4 = __attribute__((ext_vector_type(4))) float;

__device__ __forceinline__ float softplus_f(float x) {
  return (x > 20.f) ? x : log1pf(__expf(x));
}

// ---------------------------------------------------------------------------
// prep: cast x/exemplars to fp16, cb = -beta*||x||^2, ce = -beta*||e||^2,
// padded labels, zero class_sims. 16 lanes/row, 16 rows/block, 3392 blocks.
// Pad rows [NE, NE_PAD): ex_h = 0, ce = -1e30 (=> sim exactly 0), label 0.
// ---------------------------------------------------------------------------
__global__ __launch_bounds__(256) void prep_kernel(
    const float* __restrict__ x, const float* __restrict__ ex,
    const int* __restrict__ labels, const float* __restrict__ beta_raw,
    _Float16* __restrict__ ex_h, float* __restrict__ ce,
    _Float16* __restrict__ x_h, float* __restrict__ cb,
    float* __restrict__ class_sims, int* __restrict__ lab_pad)
{
  const int tid = threadIdx.x;
  const int gid = blockIdx.x * 256 + tid;
  if (gid < NB * NC) class_sims[gid] = 0.f;

  const float beta = softplus_f(beta_raw[0]);

  const int row = blockIdx.x * 16 + (tid >> 4);  // 3392*16 = 54272 = NE_PAD + NB
  const int l16 = tid & 15;

  if (row < NE_PAD) {
    float4 v = make_float4(0.f, 0.f, 0.f, 0.f);
    if (row < NE) v = ((const float4*)ex)[row * 16 + l16];
    half4v hv = { (_Float16)v.x, (_Float16)v.y, (_Float16)v.z, (_Float16)v.w };
    *(half4v*)(ex_h + (size_t)row * KD + l16 * 4) = hv;
    float s = v.x*v.x + v.y*v.y + v.z*v.z + v.w*v.w;
    #pragma unroll
    for (int m = 1; m < 16; m <<= 1) s += __shfl_xor(s, m, 64);
    if (l16 == 0) ce[row] = (row < NE) ? (-beta * s) : -1e30f;
    if (l16 == 1) lab_pad[row] = (row < NE) ? labels[row] : 0;
  } else {
    const int rx = row - NE_PAD;  // [0, NB)
    float4 v = ((const float4*)x)[rx * 16 + l16];
    half4v hv = { (_Float16)v.x, (_Float16)v.y, (_Float16)v.z, (_Float16)v.w };
    *(half4v*)(x_h + (size_t)rx * KD + l16 * 4) = hv;
    float s = v.x*v.x + v.y*v.y + v.z*v.z + v.w*v.w;
    #pragma unroll
    for (int m = 1; m < 16; m <<= 1) s += __shfl_xor(s, m, 64);
    if (l16 == 0) cb[rx] = -beta * s;
  }
}

// ---------------------------------------------------------------------------
// main: 1664 blocks = 8 XCDs x (13 chunks x 16 btiles). xcd = id&7, j = id>>3,
// chunk = xcd + 8*(j%13), btile = j/13. Block = 4 waves; wave w owns batch cols
// [btile*64+16w, +16) (B-frags from x_h, loaded once).
// Pipeline (distance-2 prefetch, double LDS buffer, 1 barrier/stage):
//   prologue: load st0,st1 -> reg sets; write st0 -> buf0; barrier.
//   stage st: issue loads st+2 -> regs[st&1]; compute 4 subtiles from buf[st&1];
//             write regs[(st+1)&1] -> buf[(st+1)&1]; barrier.
// Subtile: ae from LDS (padded rows, 2-way banks = free), ce/lab LDS broadcast,
//   MFMA1 16x16x32 -> d[e][b]; p = exp(min(2*beta*d + cb + ce, 0)) fp16
//   (= the 16x16x16 B-frag); MFMA2 vs onehot labels -> acc[c][b] in AGPRs.
// Flush: one relaxed global fp32 atomic per (b, c<10) cell. NO fences.
// ---------------------------------------------------------------------------
__global__ __launch_bounds__(256) void main_kernel(
    const _Float16* __restrict__ ex_h, const float* __restrict__ ce,
    const _Float16* __restrict__ x_h, const float* __restrict__ cb,
    const int* __restrict__ lab_pad, const float* __restrict__ beta_raw,
    float* __restrict__ class_sims)
{
  __shared__ _Float16 Ah[2][SROWS * LROW];
  __shared__ float    Ce[2][SROWS];
  __shared__ int      Lb[2][SROWS];

  const int tid  = threadIdx.x;
  const int wave = tid >> 6;
  const int lane = tid & 63;
  const int l15  = lane & 15;
  const int quad = lane >> 4;

  const int id    = blockIdx.x;
  const int xcd   = id & 7;
  const int j     = id >> 3;
  const int chunk = xcd + 8 * (j % 13);
  const int btile = j / 13;
  const int e0    = chunk * 512;
  const int bm    = btile * 64 + wave * 16;

  const float beta = softplus_f(beta_raw[0]);
  const float s2 = 2.f * beta;

  // x B-frags: B[k=quad*8+j][n=l15] -> x_h row-major, loaded once per wave.
  const half8* xrow = (const half8*)(x_h + (size_t)(bm + l15) * KD);
  const half8 bx0 = xrow[quad];
  const half8 bx1 = xrow[quad + 4];
  const float cbl = cb[bm + l15];

  // stage-load lane constants: thread t moves 32 B of row (t>>2), halfs [(t&3)*16..)
  const int srow = tid >> 2;
  const int scol = tid & 3;
  const _Float16* gsrc = ex_h + (size_t)(e0 + srow) * KD + scol * 16;
  const int lofs = srow * LROW + scol * 16;

  // two prefetch register sets (distance-2 pipeline)
  half8 pa[2], pb[2];
  float pc[2] = {0.f, 0.f};
  int   pl[2] = {0, 0};

  // ---- prologue: issue stage 0 and stage 1 loads; write stage 0 -> buf 0 ----
  pa[0] = *(const half8*)(gsrc);
  pb[0] = *(const half8*)(gsrc + 8);
  if (wave == 0) pc[0] = ce[e0 + lane];
  if (wave == 1) pl[0] = lab_pad[e0 + lane];
  pa[1] = *(const half8*)(gsrc + SROWS * KD);
  pb[1] = *(const half8*)(gsrc + SROWS * KD + 8);
  if (wave == 0) pc[1] = ce[e0 + SROWS + lane];
  if (wave == 1) pl[1] = lab_pad[e0 + SROWS + lane];

  *(half8*)(&Ah[0][lofs])     = pa[0];
  *(half8*)(&Ah[0][lofs + 8]) = pb[0];
  if (wave == 0) Ce[0][lane] = pc[0];
  if (wave == 1) Lb[0][lane] = pl[0];
  __syncthreads();

  floatx4 acc = {0.f, 0.f, 0.f, 0.f};

  #pragma unroll
  for (int st = 0; st < NSTAGE; ++st) {
    const int b = st & 1;

    // issue stage st+2 loads into the register set whose data is already in LDS
    if (st + 2 < NSTAGE) {
      const _Float16* g = gsrc + (size_t)(st + 2) * SROWS * KD;
      pa[b] = *(const half8*)(g);
      pb[b] = *(const half8*)(g + 8);
      if (wave == 0) pc[b] = ce[e0 + (st + 2) * SROWS + lane];
      if (wave == 1) pl[b] = lab_pad[e0 + (st + 2) * SROWS + lane];
    }

    // compute 4 subtiles of 16 e-rows from LDS buf b
    #pragma unroll
    for (int sub = 0; sub < 4; ++sub) {
      const int abase = (sub * 16 + l15) * LROW + quad * 8;
      const half8 ae0 = *(const half8*)(&Ah[b][abase]);
      const half8 ae1 = *(const half8*)(&Ah[b][abase + 32]);
      const float4 ce4 = *(const float4*)(&Ce[b][sub * 16 + quad * 4]);
      const int4   lb4 = *(const int4*)(&Lb[b][sub * 16 + quad * 4]);

      floatx4 d = {0.f, 0.f, 0.f, 0.f};
      d = __builtin_amdgcn_mfma_f32_16x16x32_f16(ae0, bx0, d, 0, 0, 0);
      d = __builtin_amdgcn_mfma_f32_16x16x32_f16(ae1, bx1, d, 0, 0, 0);

      const float cef[4] = { ce4.x, ce4.y, ce4.z, ce4.w };
      half4v p;
      #pragma unroll
      for (int r = 0; r < 4; ++r) {
        const float t = fminf(fmaf(s2, d[r], cbl + cef[r]), 0.f);  // -beta*max(d2,0)
        p[r] = (_Float16)__expf(t);
      }

      half4v oh;
      oh[0] = (lb4.x == l15) ? (_Float16)1.f : (_Float16)0.f;
      oh[1] = (lb4.y == l15) ? (_Float16)1.f : (_Float16)0.f;
      oh[2] = (lb4.z == l15) ? (_Float16)1.f : (_Float16)0.f;
      oh[3] = (lb4.w == l15) ? (_Float16)1.f : (_Float16)0.f;

      acc = __builtin_amdgcn_mfma_f32_16x16x16f16(oh, p, acc, 0, 0, 0);
    }

    // write stage st+1 (held in regs[(st+1)&1]) into buf[(st+1)&1].
    // Safe without a pre-barrier: that buffer was last READ in stage st-1, and
    // every wave passed the barrier at the end of stage st-1 before entering st.
    if (st + 1 < NSTAGE) {
      const int nb = (st + 1) & 1;
      *(half8*)(&Ah[nb][lofs])     = pa[nb];
      *(half8*)(&Ah[nb][lofs + 8]) = pb[nb];
      if (wave == 0) Ce[nb][lane] = pc[nb];
      if (wave == 1) Lb[nb][lane] = pl[nb];
      __syncthreads();
    }
  }

  // acc: lane holds class_part[c = quad*4+r][b = l15] -> relaxed global atomics.
  #pragma unroll
  for (int r = 0; r < 4; ++r) {
    const int c = quad * 4 + r;
    if (c < NC) {
      __hip_atomic_fetch_add(&class_sims[(size_t)(bm + l15) * NC + c], acc[r],
                             __ATOMIC_RELAXED, __HIP_MEMORY_SCOPE_AGENT);
    }
  }
}

// ---------------------------------------------------------------------------
// finalize: logits = log(class_sims + eps). Kernel boundary orders the atomics.
// ---------------------------------------------------------------------------
__global__ __launch_bounds__(256) void log_kernel(
    const float* __restrict__ cs, float* __restrict__ out)
{
  const int i = blockIdx.x * 256 + threadIdx.x;
  if (i < NB * NC) out[i] = __logf(cs[i] + 1e-12f);
}

extern "C" void kernel_launch(void* const* d_in, const int* in_sizes, int n_in,
                              void* d_out, int out_size, void* d_ws, size_t ws_size,
                              hipStream_t stream)
{
  const float* x        = (const float*)d_in[0];
  const float* ex       = (const float*)d_in[1];
  const int*   labels   = (const int*)d_in[2];
  const float* beta_raw = (const float*)d_in[3];
  float* out = (float*)d_out;

  // Workspace layout (~7.42 MB total):
  char* ws = (char*)d_ws;
  _Float16* ex_h       = (_Float16*)ws;             // 53248*64*2 = 6,815,744 B
  float*    ce         = (float*)(ws + 6815744);    //   212,992 B
  _Float16* x_h        = (_Float16*)(ws + 7028736); //   131,072 B
  float*    cb         = (float*)(ws + 7159808);    //     4,096 B
  float*    class_sims = (float*)(ws + 7163904);    //    40,960 B
  int*      lab_pad    = (int*)(ws + 7204864);      //   212,992 B  (end: 7,417,856)

  prep_kernel<<<3392, 256, 0, stream>>>(x, ex, labels, beta_raw,
                                        ex_h, ce, x_h, cb, class_sims, lab_pad);
  main_kernel<<<1664, 256, 0, stream>>>(ex_h, ce, x_h, cb, lab_pad, beta_raw,
                                        class_sims);
  log_kernel<<<40, 256, 0, stream>>>(class_sims, out);
}